// Round 7
// baseline (661.403 us; speedup 1.0000x reference)
//
#include <hip/hip_runtime.h>
#include <stdint.h>

typedef __attribute__((ext_vector_type(8))) short short8;
typedef __attribute__((ext_vector_type(8))) unsigned short ushort8;
typedef __attribute__((ext_vector_type(4))) float f32x4;

__device__ __forceinline__ ushort f2bf(float f) {
  union { float f; uint32_t u; } v; v.f = f;
  uint32_t r = v.u + 0x7FFFu + ((v.u >> 16) & 1u);
  return (ushort)(r >> 16);
}

__device__ __forceinline__ float fexp2(float x) {
  return __builtin_amdgcn_exp2f(x);  // v_exp_f32 (input in base-2 domain)
}

__device__ __forceinline__ void gld16(const ushort* g, ushort* l) {
  __builtin_amdgcn_global_load_lds((const __attribute__((address_space(1))) void*)g,
                                   (__attribute__((address_space(3))) void*)l, 16, 0, 0);
}

// ---------------- fp32 -> bf16 elementwise ----------------
__global__ __launch_bounds__(256) void k_f32_to_bf16(const float* __restrict__ in,
                                                     ushort* __restrict__ out, long n) {
  long i = ((long)blockIdx.x * 256 + threadIdx.x) * 8;
  if (i >= n) return;
  float4 a = *(const float4*)(in + i);
  float4 b = *(const float4*)(in + i + 4);
  ushort8 o;
  o[0] = f2bf(a.x); o[1] = f2bf(a.y); o[2] = f2bf(a.z); o[3] = f2bf(a.w);
  o[4] = f2bf(b.x); o[5] = f2bf(b.y); o[6] = f2bf(b.z); o[7] = f2bf(b.w);
  *(ushort8*)(out + i) = o;
}

// ---------------- fp32 (R x C) -> bf16 transposed (C x R), out row-stride R ----------------
__global__ __launch_bounds__(256) void k_w_transpose(const float* __restrict__ in,
                                                     ushort* __restrict__ out, int R, int C) {
  __shared__ float t[32][33];
  int tx = threadIdx.x & 31, ty = threadIdx.x >> 5;
  int r0 = blockIdx.y * 32, c0 = blockIdx.x * 32;
#pragma unroll
  for (int i = 0; i < 4; i++)
    t[ty + i * 8][tx] = in[(size_t)(r0 + ty + i * 8) * C + c0 + tx];
  __syncthreads();
#pragma unroll
  for (int i = 0; i < 4; i++)
    out[(size_t)(c0 + ty + i * 8) * R + r0 + tx] = f2bf(t[tx][ty + i * 8]);
}

// ---------------- V slice of QKV (B,T,3072) -> VT (B,G,HD,T) bf16 ----------------
__global__ __launch_bounds__(256) void k_v_transpose(const ushort* __restrict__ qkv,
                                                     ushort* __restrict__ out) {
  __shared__ ushort t[32][33];
  int tx = threadIdx.x & 31, ty = threadIdx.x >> 5;
  int t0 = blockIdx.x * 32, d0 = blockIdx.y * 32;
  int b = blockIdx.z >> 2, g = blockIdx.z & 3;
#pragma unroll
  for (int i = 0; i < 4; i++)
    t[ty + i * 8][tx] =
        qkv[((size_t)b * 2048 + t0 + ty + i * 8) * 3072 + 2560 + g * 128 + d0 + tx];
  __syncthreads();
#pragma unroll
  for (int i = 0; i < 4; i++)
    out[(((size_t)b * 4 + g) * 128 + d0 + ty + i * 8) * 2048 + t0 + tx] = t[tx][ty + i * 8];
}

// ---------------- GEMM: C[M,N] = A[M,K] @ BT[N,K]^T, bf16 in, bf16/f32 out ----------------
template <int F32OUT>
__global__ __launch_bounds__(256) void k_gemm(const ushort* __restrict__ A,
                                              const ushort* __restrict__ BT,
                                              void* __restrict__ C, int M, int N, int K) {
  __shared__ ushort As[128 * 32];
  __shared__ ushort Bs[128 * 32];
  const int tid = threadIdx.x;
  const int lane = tid & 63;
  const int wid = tid >> 6;
  const int m0 = blockIdx.y * 128, n0 = blockIdx.x * 128;
  const int wr = (wid >> 1) * 64, wc = (wid & 1) * 64;
  const int l15 = lane & 15, l4 = lane >> 4;
  f32x4 acc[4][4] = {};

  for (int kt = 0; kt < K; kt += 32) {
#pragma unroll
    for (int i = 0; i < 2; i++) {
      int c = i * 256 + tid;
      int row = c >> 2, off = (c & 3) * 8;
      gld16(&A[(size_t)(m0 + row) * K + kt + off], &As[c * 8]);
      gld16(&BT[(size_t)(n0 + row) * K + kt + off], &Bs[c * 8]);
    }
    __syncthreads();
    short8 af[4], bfr[4];
#pragma unroll
    for (int x = 0; x < 4; x++) {
      af[x]  = *(const short8*)&As[(wr + x * 16 + l15) * 32 + l4 * 8];
      bfr[x] = *(const short8*)&Bs[(wc + x * 16 + l15) * 32 + l4 * 8];
    }
#pragma unroll
    for (int mf = 0; mf < 4; mf++)
#pragma unroll
      for (int nf = 0; nf < 4; nf++)
        acc[mf][nf] = __builtin_amdgcn_mfma_f32_16x16x32_bf16(af[mf], bfr[nf], acc[mf][nf], 0, 0, 0);
    __syncthreads();
  }
#pragma unroll
  for (int mf = 0; mf < 4; mf++)
#pragma unroll
    for (int nf = 0; nf < 4; nf++)
#pragma unroll
      for (int r = 0; r < 4; r++) {
        int m = m0 + wr + mf * 16 + l4 * 4 + r;
        int n = n0 + wc + nf * 16 + l15;
        if (F32OUT)
          ((float*)C)[(size_t)m * N + n] = acc[mf][nf][r];
        else
          ((ushort*)C)[(size_t)m * N + n] = f2bf(acc[mf][nf][r]);
      }
}

// ---------------- causal GQA flash attention: 2-wave blocks, paired q-tiles -------
// Block (p,bh): q-tiles j=63-p then j=p (sum of work = 33 tiles, uniform across p).
// Within each q-tile, wave w handles KV tiles it%2==w; the 2 partial (o,m,l) are
// merged through LDS (flash-decoding, 1 merge). 2048 blocks x 2 waves = 16 waves/CU
// (needs VGPR<=128; no launch_bounds min-occupancy -> no forced spill, cf. R3).
// exp in base-2 domain (SCALE2 = SCALE*log2e); T13 defer-max skips o-rescale when
// tile max <= m + 11.5 (wave-uniform branch).
__global__ __launch_bounds__(128) void k_attn(const ushort* __restrict__ QKV,
                                              const ushort* __restrict__ VT,
                                              ushort* __restrict__ O) {
  const int T = 2048, HD = 128, G = 4, H = 16, RS = 3072;
  const float SCALE2 = 0.08838834764831845f * 1.4426950408889634f;
  int bid = blockIdx.x;
  int p = bid >> 6;          // 0..31
  int bh = bid & 63;
  int h = bh & 15, b = bh >> 4;
  int g = h & 3;
  int tid = threadIdx.x, wid = tid >> 6, lane = tid & 63;
  int l15 = lane & 15, l4 = lane >> 4;

  // LDS: [0,16896) Po f32[32][132]; [16896,17024) Pm; [17024,17152) Pl.
  // P-stage buffers (2 x 4608B) union with the front of Po (disjoint in time).
  __shared__ __align__(16) char smem[17152];
  ushort* Pw = (ushort*)smem + wid * (32 * 72);
  float* Po = (float*)smem;
  float* Pm = (float*)(smem + 16896);
  float* Pl = (float*)(smem + 17024);

  const ushort* Qb = &QKV[(size_t)b * T * RS + h * HD];
  const ushort* Kb = &QKV[(size_t)b * T * RS + 2048 + g * HD];
  const ushort* Vb = &VT[((size_t)b * G + g) * (size_t)HD * T];

  for (int half = 0; half < 2; half++) {
    int j = half ? p : (63 - p);
    int qw = j * 32;

    short8 qf[2][4];
#pragma unroll
    for (int mf = 0; mf < 2; mf++)
#pragma unroll
      for (int kf = 0; kf < 4; kf++)
        qf[mf][kf] = *(const short8*)&Qb[(size_t)(qw + mf * 16 + l15) * RS + kf * 32 + l4 * 8];

    f32x4 o[2][8] = {};
    float mrow[8], lrow[8];
#pragma unroll
    for (int i = 0; i < 8; i++) { mrow[i] = -3e38f; lrow[i] = 0.f; }

    int ntiles = (qw >> 6) + 1;
    for (int it = wid; it < ntiles; it += 2) {
      int t0 = it * 64;
      f32x4 s[2][4] = {};
#pragma unroll
      for (int kf = 0; kf < 4; kf++) {
#pragma unroll
        for (int nf = 0; nf < 4; nf++) {
          short8 bk = *(const short8*)&Kb[(size_t)(t0 + nf * 16 + l15) * RS + kf * 32 + l4 * 8];
          s[0][nf] = __builtin_amdgcn_mfma_f32_16x16x32_bf16(qf[0][kf], bk, s[0][nf], 0, 0, 0);
          s[1][nf] = __builtin_amdgcn_mfma_f32_16x16x32_bf16(qf[1][kf], bk, s[1][nf], 0, 0, 0);
        }
      }
      bool needmask = (t0 + 63 > qw);
#pragma unroll
      for (int mf = 0; mf < 2; mf++)
#pragma unroll
        for (int nf = 0; nf < 4; nf++)
#pragma unroll
          for (int r = 0; r < 4; r++) {
            float v = s[mf][nf][r] * SCALE2;
            if (needmask) {
              int qq = qw + mf * 16 + l4 * 4 + r;
              int kk = t0 + nf * 16 + l15;
              if (kk > qq) v = -1e30f;
            }
            s[mf][nf][r] = v;
          }
      // tile row-max (row-uniform across the 16 lanes after shfl reduce)
      float x8[8];
      bool ok = true;
#pragma unroll
      for (int mf = 0; mf < 2; mf++)
#pragma unroll
        for (int r = 0; r < 4; r++) {
          int i = mf * 4 + r;
          float x = fmaxf(fmaxf(s[mf][0][r], s[mf][1][r]), fmaxf(s[mf][2][r], s[mf][3][r]));
          x = fmaxf(x, __shfl_xor(x, 1));
          x = fmaxf(x, __shfl_xor(x, 2));
          x = fmaxf(x, __shfl_xor(x, 4));
          x = fmaxf(x, __shfl_xor(x, 8));
          x8[i] = x;
          ok = ok && (x - mrow[i] <= 11.5f);
        }
      if (!__all(ok)) {  // T13: rescale only when tile max grew past threshold
#pragma unroll
        for (int i = 0; i < 8; i++) {
          float mn = fmaxf(mrow[i], x8[i]);
          float sc = fexp2(mrow[i] - mn);
          mrow[i] = mn;
          lrow[i] *= sc;
#pragma unroll
          for (int nfo = 0; nfo < 8; nfo++)
            o[i >> 2][nfo][i & 3] *= sc;
        }
      }
      // p = 2^(s - m); per-lane partial row-sums (16-lane reduce deferred)
#pragma unroll
      for (int mf = 0; mf < 2; mf++)
#pragma unroll
        for (int nf = 0; nf < 4; nf++)
#pragma unroll
          for (int r = 0; r < 4; r++) {
            float pq = fexp2(s[mf][nf][r] - mrow[mf * 4 + r]);
            s[mf][nf][r] = pq;
            lrow[mf * 4 + r] += pq;
          }
#pragma unroll
      for (int mf = 0; mf < 2; mf++)
#pragma unroll
        for (int nf = 0; nf < 4; nf++)
#pragma unroll
          for (int r = 0; r < 4; r++)
            Pw[(mf * 16 + l4 * 4 + r) * 72 + nf * 16 + l15] = f2bf(s[mf][nf][r]);
#pragma unroll
      for (int kf = 0; kf < 2; kf++) {
        short8 pa0 = *(const short8*)&Pw[(l15) * 72 + kf * 32 + l4 * 8];
        short8 pa1 = *(const short8*)&Pw[(16 + l15) * 72 + kf * 32 + l4 * 8];
#pragma unroll
        for (int nfo = 0; nfo < 8; nfo++) {
          short8 bv = *(const short8*)&Vb[(size_t)(nfo * 16 + l15) * T + t0 + kf * 32 + l4 * 8];
          o[0][nfo] = __builtin_amdgcn_mfma_f32_16x16x32_bf16(pa0, bv, o[0][nfo], 0, 0, 0);
          o[1][nfo] = __builtin_amdgcn_mfma_f32_16x16x32_bf16(pa1, bv, o[1][nfo], 0, 0, 0);
        }
      }
    }

    // finish deferred 16-lane reduction of l (row-uniform after this)
#pragma unroll
    for (int i = 0; i < 8; i++) {
      float x = lrow[i];
      x += __shfl_xor(x, 1);
      x += __shfl_xor(x, 2);
      x += __shfl_xor(x, 4);
      x += __shfl_xor(x, 8);
      lrow[i] = x;
    }

    __syncthreads();  // both waves past P-stage use; LDS switches to combine role
    if (wid == 1) {
#pragma unroll
      for (int mf = 0; mf < 2; mf++)
#pragma unroll
        for (int nfo = 0; nfo < 8; nfo++)
#pragma unroll
          for (int r = 0; r < 4; r++)
            Po[(mf * 16 + l4 * 4 + r) * 132 + nfo * 16 + l15] = o[mf][nfo][r];
      if (l15 == 0) {
#pragma unroll
        for (int mf = 0; mf < 2; mf++)
#pragma unroll
          for (int r = 0; r < 4; r++) {
            int row = mf * 16 + l4 * 4 + r;
            Pm[row] = mrow[mf * 4 + r];
            Pl[row] = lrow[mf * 4 + r];
          }
      }
    }
    __syncthreads();
    if (wid == 0) {
#pragma unroll
      for (int mf = 0; mf < 2; mf++)
#pragma unroll
        for (int r = 0; r < 4; r++) {
          int i = mf * 4 + r;
          int row = mf * 16 + l4 * 4 + r;
          float pm = Pm[row];
          float pl = Pl[row];
          float M = fmaxf(mrow[i], pm);
          float a = fexp2(mrow[i] - M);
          float bfac = fexp2(pm - M);
          float l = lrow[i] * a + pl * bfac;
          float inv = 1.0f / l;
#pragma unroll
          for (int nfo = 0; nfo < 8; nfo++) {
            float pv = Po[row * 132 + nfo * 16 + l15];
            float val = (o[mf][nfo][r] * a + pv * bfac) * inv;
            O[(((size_t)b * T + qw + row) * H + h) * HD + nfo * 16 + l15] = f2bf(val);
          }
        }
    }
    __syncthreads();  // wave0 done reading Po before next half's P-stage writes
  }
}

extern "C" void kernel_launch(void* const* d_in, const int* in_sizes, int n_in,
                              void* d_out, int out_size, void* d_ws, size_t ws_size,
                              hipStream_t stream) {
  const float* x   = (const float*)d_in[0];
  const float* w_q = (const float*)d_in[1];
  const float* w_k = (const float*)d_in[2];
  const float* w_v = (const float*)d_in[3];
  const float* w_o = (const float*)d_in[4];

  char* ws = (char*)d_ws;
  ushort* xbf  = (ushort*)(ws);                // 32MB (reused as attn out)
  ushort* wkvT = (ushort*)(ws + 33554432ul);   // 12MB: [wq|wk|wv]^T = [3072,2048]
  ushort* woT  = (ushort*)(ws + 46137344ul);   // 8MB
  ushort* qkvb = (ushort*)(ws + 54525952ul);   // 48MB: (B,T,3072)
  ushort* VTb  = (ushort*)(ws + 104857600ul);  // 8MB  (total 113,246,208 B)
  ushort* attn = xbf;

  k_f32_to_bf16<<<8192, 256, 0, stream>>>(x, xbf, 16777216L);
  k_w_transpose<<<dim3(64, 64), 256, 0, stream>>>(w_q, wkvT, 2048, 2048);
  k_w_transpose<<<dim3(16, 64), 256, 0, stream>>>(w_k, wkvT + 2048ul * 2048, 2048, 512);
  k_w_transpose<<<dim3(16, 64), 256, 0, stream>>>(w_v, wkvT + 2560ul * 2048, 2048, 512);
  k_w_transpose<<<dim3(64, 64), 256, 0, stream>>>(w_o, woT, 2048, 2048);

  // merged QKV projection: one dispatch, N=3072
  k_gemm<0><<<dim3(24, 64), 256, 0, stream>>>(xbf, wkvT, qkvb, 8192, 3072, 2048);

  k_v_transpose<<<dim3(64, 4, 16), 256, 0, stream>>>(qkvb, VTb);

  k_attn<<<2048, 128, 0, stream>>>(qkvb, VTb, attn);

  k_gemm<1><<<dim3(16, 64), 256, 0, stream>>>(attn, woT, (float*)d_out, 8192, 2048, 2048);
}

// Round 8
// 556.509 us; speedup vs baseline: 1.1885x; 1.1885x over previous
//
#include <hip/hip_runtime.h>
#include <stdint.h>

typedef __attribute__((ext_vector_type(8))) short short8;
typedef __attribute__((ext_vector_type(8))) unsigned short ushort8;
typedef __attribute__((ext_vector_type(4))) float f32x4;

__device__ __forceinline__ ushort f2bf(float f) {
  union { float f; uint32_t u; } v; v.f = f;
  uint32_t r = v.u + 0x7FFFu + ((v.u >> 16) & 1u);
  return (ushort)(r >> 16);
}

__device__ __forceinline__ void gld16(const ushort* g, ushort* l) {
  __builtin_amdgcn_global_load_lds((const __attribute__((address_space(1))) void*)g,
                                   (__attribute__((address_space(3))) void*)l, 16, 0, 0);
}

// ---------------- fp32 -> bf16 elementwise ----------------
__global__ __launch_bounds__(256) void k_f32_to_bf16(const float* __restrict__ in,
                                                     ushort* __restrict__ out, long n) {
  long i = ((long)blockIdx.x * 256 + threadIdx.x) * 8;
  if (i >= n) return;
  float4 a = *(const float4*)(in + i);
  float4 b = *(const float4*)(in + i + 4);
  ushort8 o;
  o[0] = f2bf(a.x); o[1] = f2bf(a.y); o[2] = f2bf(a.z); o[3] = f2bf(a.w);
  o[4] = f2bf(b.x); o[5] = f2bf(b.y); o[6] = f2bf(b.z); o[7] = f2bf(b.w);
  *(ushort8*)(out + i) = o;
}

// ---------------- fp32 (R x C) -> bf16 transposed (C x R), out row-stride R ----------------
__global__ __launch_bounds__(256) void k_w_transpose(const float* __restrict__ in,
                                                     ushort* __restrict__ out, int R, int C) {
  __shared__ float t[32][33];
  int tx = threadIdx.x & 31, ty = threadIdx.x >> 5;
  int r0 = blockIdx.y * 32, c0 = blockIdx.x * 32;
#pragma unroll
  for (int i = 0; i < 4; i++)
    t[ty + i * 8][tx] = in[(size_t)(r0 + ty + i * 8) * C + c0 + tx];
  __syncthreads();
#pragma unroll
  for (int i = 0; i < 4; i++)
    out[(size_t)(c0 + ty + i * 8) * R + r0 + tx] = f2bf(t[tx][ty + i * 8]);
}

// ---------------- V slice of QKV (B,T,3072) -> VT (B,G,HD,T) bf16 ----------------
__global__ __launch_bounds__(256) void k_v_transpose(const ushort* __restrict__ qkv,
                                                     ushort* __restrict__ out) {
  __shared__ ushort t[32][33];
  int tx = threadIdx.x & 31, ty = threadIdx.x >> 5;
  int t0 = blockIdx.x * 32, d0 = blockIdx.y * 32;
  int b = blockIdx.z >> 2, g = blockIdx.z & 3;
#pragma unroll
  for (int i = 0; i < 4; i++)
    t[ty + i * 8][tx] =
        qkv[((size_t)b * 2048 + t0 + ty + i * 8) * 3072 + 2560 + g * 128 + d0 + tx];
  __syncthreads();
#pragma unroll
  for (int i = 0; i < 4; i++)
    out[(((size_t)b * 4 + g) * 128 + d0 + ty + i * 8) * 2048 + t0 + tx] = t[tx][ty + i * 8];
}

// ---------------- GEMM: C[M,N] = A[M,K] @ BT[N,K]^T, bf16 in, bf16/f32 out ----------------
// T1 XCD-aware block swizzle (grid must be %8==0): consecutive blocks per XCD
// share A panels -> L2 locality.
template <int F32OUT>
__global__ __launch_bounds__(256) void k_gemm(const ushort* __restrict__ A,
                                              const ushort* __restrict__ BT,
                                              void* __restrict__ C, int M, int N, int K) {
  __shared__ ushort As[128 * 32];
  __shared__ ushort Bs[128 * 32];
  const int tid = threadIdx.x;
  const int lane = tid & 63;
  const int wid = tid >> 6;
  int nwg = gridDim.x * gridDim.y;
  int lin = blockIdx.y * gridDim.x + blockIdx.x;
  int swz = (lin & 7) * (nwg >> 3) + (lin >> 3);
  int bx = swz % gridDim.x;
  int by = swz / gridDim.x;
  const int m0 = by * 128, n0 = bx * 128;
  const int wr = (wid >> 1) * 64, wc = (wid & 1) * 64;
  const int l15 = lane & 15, l4 = lane >> 4;
  f32x4 acc[4][4] = {};

  for (int kt = 0; kt < K; kt += 32) {
#pragma unroll
    for (int i = 0; i < 2; i++) {
      int c = i * 256 + tid;
      int row = c >> 2, off = (c & 3) * 8;
      gld16(&A[(size_t)(m0 + row) * K + kt + off], &As[c * 8]);
      gld16(&BT[(size_t)(n0 + row) * K + kt + off], &Bs[c * 8]);
    }
    __syncthreads();
    short8 af[4], bfr[4];
#pragma unroll
    for (int x = 0; x < 4; x++) {
      af[x]  = *(const short8*)&As[(wr + x * 16 + l15) * 32 + l4 * 8];
      bfr[x] = *(const short8*)&Bs[(wc + x * 16 + l15) * 32 + l4 * 8];
    }
#pragma unroll
    for (int mf = 0; mf < 4; mf++)
#pragma unroll
      for (int nf = 0; nf < 4; nf++)
        acc[mf][nf] = __builtin_amdgcn_mfma_f32_16x16x32_bf16(af[mf], bfr[nf], acc[mf][nf], 0, 0, 0);
    __syncthreads();
  }
#pragma unroll
  for (int mf = 0; mf < 4; mf++)
#pragma unroll
    for (int nf = 0; nf < 4; nf++)
#pragma unroll
      for (int r = 0; r < 4; r++) {
        int m = m0 + wr + mf * 16 + l4 * 4 + r;
        int n = n0 + wc + nf * 16 + l15;
        if (F32OUT)
          ((float*)C)[(size_t)m * N + n] = acc[mf][nf][r];
        else
          ((ushort*)C)[(size_t)m * N + n] = f2bf(acc[mf][nf][r]);
      }
}

// ---------------- causal GQA flash attention: 1 wave per block, paired q-tiles ----
// EXACT round-5 structure (verified 288us, VGPR 124): block (p,bh) processes q-tile
// j=63-p then j=p; w(63-p)+w(p)=33 tiles for all p -> uniform wave lengths, no tail.
// Single delta vs R5: softmax in base-2 domain (exp2f, SCALE2=SCALE*log2e).
// K/V read directly from global (L2/L3-resident). No barriers, no setprio.
__global__ __launch_bounds__(64) void k_attn(const ushort* __restrict__ QKV,
                                             const ushort* __restrict__ VT,
                                             ushort* __restrict__ O) {
  const int T = 2048, HD = 128, G = 4, H = 16, RS = 3072;
  const float SCALE2 = 0.08838834764831845f * 1.4426950408889634f;
  int bid = blockIdx.x;
  int p = bid >> 6;          // 0..31
  int bh = bid & 63;
  int h = bh & 15, b = bh >> 4;
  int g = h & 3;
  int lane = threadIdx.x;
  int l15 = lane & 15, l4 = lane >> 4;

  __shared__ ushort Ps[32 * 72];

  const ushort* Qb = &QKV[(size_t)b * T * RS + h * HD];
  const ushort* Kb = &QKV[(size_t)b * T * RS + 2048 + g * HD];
  const ushort* Vb = &VT[((size_t)b * G + g) * (size_t)HD * T];

  for (int half = 0; half < 2; half++) {
    int j = half ? p : (63 - p);
    int qw = j * 32;

    short8 qf[2][4];
#pragma unroll
    for (int mf = 0; mf < 2; mf++)
#pragma unroll
      for (int kf = 0; kf < 4; kf++)
        qf[mf][kf] = *(const short8*)&Qb[(size_t)(qw + mf * 16 + l15) * RS + kf * 32 + l4 * 8];

    f32x4 o[2][8] = {};
    float mrow[8], lrow[8];
#pragma unroll
    for (int i = 0; i < 8; i++) { mrow[i] = -3e38f; lrow[i] = 0.f; }

    int ntiles = (qw >> 6) + 1;
    for (int it = 0; it < ntiles; ++it) {
      int t0 = it * 64;
      f32x4 s[2][4] = {};
#pragma unroll
      for (int kf = 0; kf < 4; kf++) {
#pragma unroll
        for (int nf = 0; nf < 4; nf++) {
          short8 bk = *(const short8*)&Kb[(size_t)(t0 + nf * 16 + l15) * RS + kf * 32 + l4 * 8];
          s[0][nf] = __builtin_amdgcn_mfma_f32_16x16x32_bf16(qf[0][kf], bk, s[0][nf], 0, 0, 0);
          s[1][nf] = __builtin_amdgcn_mfma_f32_16x16x32_bf16(qf[1][kf], bk, s[1][nf], 0, 0, 0);
        }
      }
      bool needmask = (t0 + 63 > qw);
#pragma unroll
      for (int mf = 0; mf < 2; mf++)
#pragma unroll
        for (int nf = 0; nf < 4; nf++)
#pragma unroll
          for (int r = 0; r < 4; r++) {
            float v = s[mf][nf][r] * SCALE2;
            if (needmask) {
              int qq = qw + mf * 16 + l4 * 4 + r;
              int kk = t0 + nf * 16 + l15;
              if (kk > qq) v = -1e30f;
            }
            s[mf][nf][r] = v;
          }
      float scs[8];
#pragma unroll
      for (int mf = 0; mf < 2; mf++)
#pragma unroll
        for (int r = 0; r < 4; r++) {
          int i = mf * 4 + r;
          float x = fmaxf(fmaxf(s[mf][0][r], s[mf][1][r]), fmaxf(s[mf][2][r], s[mf][3][r]));
          x = fmaxf(x, __shfl_xor(x, 1));
          x = fmaxf(x, __shfl_xor(x, 2));
          x = fmaxf(x, __shfl_xor(x, 4));
          x = fmaxf(x, __shfl_xor(x, 8));
          float mn = fmaxf(mrow[i], x);
          scs[i] = exp2f(mrow[i] - mn);
          mrow[i] = mn;
        }
      // per-lane partial row-sums; 16-lane reduction deferred to epilogue
      float rs[8];
#pragma unroll
      for (int i = 0; i < 8; i++) rs[i] = 0.f;
#pragma unroll
      for (int mf = 0; mf < 2; mf++)
#pragma unroll
        for (int nf = 0; nf < 4; nf++)
#pragma unroll
          for (int r = 0; r < 4; r++) {
            float pq = exp2f(s[mf][nf][r] - mrow[mf * 4 + r]);
            s[mf][nf][r] = pq;
            rs[mf * 4 + r] += pq;
          }
#pragma unroll
      for (int i = 0; i < 8; i++) lrow[i] = lrow[i] * scs[i] + rs[i];
#pragma unroll
      for (int mf = 0; mf < 2; mf++)
#pragma unroll
        for (int nfo = 0; nfo < 8; nfo++)
#pragma unroll
          for (int r = 0; r < 4; r++)
            o[mf][nfo][r] *= scs[mf * 4 + r];
#pragma unroll
      for (int mf = 0; mf < 2; mf++)
#pragma unroll
        for (int nf = 0; nf < 4; nf++)
#pragma unroll
          for (int r = 0; r < 4; r++)
            Ps[(mf * 16 + l4 * 4 + r) * 72 + nf * 16 + l15] = f2bf(s[mf][nf][r]);
#pragma unroll
      for (int kf = 0; kf < 2; kf++) {
        short8 pa0 = *(const short8*)&Ps[(l15) * 72 + kf * 32 + l4 * 8];
        short8 pa1 = *(const short8*)&Ps[(16 + l15) * 72 + kf * 32 + l4 * 8];
#pragma unroll
        for (int nfo = 0; nfo < 8; nfo++) {
          short8 bv = *(const short8*)&Vb[(size_t)(nfo * 16 + l15) * T + t0 + kf * 32 + l4 * 8];
          o[0][nfo] = __builtin_amdgcn_mfma_f32_16x16x32_bf16(pa0, bv, o[0][nfo], 0, 0, 0);
          o[1][nfo] = __builtin_amdgcn_mfma_f32_16x16x32_bf16(pa1, bv, o[1][nfo], 0, 0, 0);
        }
      }
    }

    // finish deferred 16-lane reduction of l
#pragma unroll
    for (int i = 0; i < 8; i++) {
      float x = lrow[i];
      x += __shfl_xor(x, 1);
      x += __shfl_xor(x, 2);
      x += __shfl_xor(x, 4);
      x += __shfl_xor(x, 8);
      lrow[i] = x;
    }
    float inv[8];
#pragma unroll
    for (int i = 0; i < 8; i++) inv[i] = 1.0f / lrow[i];
#pragma unroll
    for (int mf = 0; mf < 2; mf++)
#pragma unroll
      for (int nfo = 0; nfo < 8; nfo++)
#pragma unroll
        for (int r = 0; r < 4; r++) {
          int t = qw + mf * 16 + l4 * 4 + r;
          int d = nfo * 16 + l15;
          O[(((size_t)b * T + t) * H + h) * HD + d] = f2bf(o[mf][nfo][r] * inv[mf * 4 + r]);
        }
  }
}

extern "C" void kernel_launch(void* const* d_in, const int* in_sizes, int n_in,
                              void* d_out, int out_size, void* d_ws, size_t ws_size,
                              hipStream_t stream) {
  const float* x   = (const float*)d_in[0];
  const float* w_q = (const float*)d_in[1];
  const float* w_k = (const float*)d_in[2];
  const float* w_v = (const float*)d_in[3];
  const float* w_o = (const float*)d_in[4];

  char* ws = (char*)d_ws;
  ushort* xbf  = (ushort*)(ws);                // 32MB (reused as attn out)
  ushort* wkvT = (ushort*)(ws + 33554432ul);   // 12MB: [wq|wk|wv]^T = [3072,2048]
  ushort* woT  = (ushort*)(ws + 46137344ul);   // 8MB
  ushort* qkvb = (ushort*)(ws + 54525952ul);   // 48MB: (B,T,3072)
  ushort* VTb  = (ushort*)(ws + 104857600ul);  // 8MB  (total 113,246,208 B)
  ushort* attn = xbf;

  k_f32_to_bf16<<<8192, 256, 0, stream>>>(x, xbf, 16777216L);
  k_w_transpose<<<dim3(64, 64), 256, 0, stream>>>(w_q, wkvT, 2048, 2048);
  k_w_transpose<<<dim3(16, 64), 256, 0, stream>>>(w_k, wkvT + 2048ul * 2048, 2048, 512);
  k_w_transpose<<<dim3(16, 64), 256, 0, stream>>>(w_v, wkvT + 2560ul * 2048, 2048, 512);
  k_w_transpose<<<dim3(64, 64), 256, 0, stream>>>(w_o, woT, 2048, 2048);

  // merged QKV projection: one dispatch, N=3072
  k_gemm<0><<<dim3(24, 64), 256, 0, stream>>>(xbf, wkvT, qkvb, 8192, 3072, 2048);

  k_v_transpose<<<dim3(64, 4, 16), 256, 0, stream>>>(qkvb, VTb);

  k_attn<<<2048, 64, 0, stream>>>(qkvb, VTb, attn);

  k_gemm<1><<<dim3(16, 64), 256, 0, stream>>>(attn, woT, (float*)d_out, 8192, 2048, 2048);
}